// Round 5
// baseline (2361.425 us; speedup 1.0000x reference)
//
#include <hip/hip_runtime.h>
#include <math.h>

#define KNUM 128
#define LL   256
#define NINP 384
#define HC   64
#define NH   4
#define D2   128
#define AGG  256
#define LHC  (LL*HC)        // 16384
#define M1   (KNUM*LL)      // 32768
#define TP   16             // j columns per block in k_agg
#define KC   8              // k-chunk in k_agg phase A
#define AJ_STR (KC*64+4)    // 516: padded per-pair stride
#define XL_STR 1028         // padded xl stride: 1028 % 32 == 4 -> banks spread

// ---------------- Kernel 1: fused dual GEMM (P,Q) + bias + LN(P) + clamp(Q) ----
__global__ __launch_bounds__(256) void k_proj(
    const float* __restrict__ x1d, const float* __restrict__ Wp, const float* __restrict__ bp,
    const float* __restrict__ gp, const float* __restrict__ betap,
    const float* __restrict__ Wq, const float* __restrict__ bq,
    float* __restrict__ P, float* __restrict__ Qpre)
{
    __shared__ float Xs[64][33];
    __shared__ float Ws[32][128];
    __shared__ float Ps[64][65];
    const int t = threadIdx.x;
    const int row0 = blockIdx.x * 64;
    const int tc = t & 15, tr = t >> 4;   // thread tile: rows tr*4..+3, cols tc*8..+7
    float acc[4][8];
    #pragma unroll
    for (int a = 0; a < 4; a++)
        #pragma unroll
        for (int b = 0; b < 8; b++) acc[a][b] = 0.f;

    for (int k0 = 0; k0 < NINP; k0 += 32) {
        for (int idx = t; idx < 64 * 32; idx += 256) {
            int r = idx >> 5, kk = idx & 31;
            Xs[r][kk] = x1d[(size_t)(row0 + r) * NINP + k0 + kk];
        }
        for (int idx = t; idx < 32 * 128; idx += 256) {
            int kk = idx >> 7, cc = idx & 127;
            Ws[kk][cc] = (cc < 64) ? Wp[(size_t)(k0 + kk) * HC + cc]
                                   : Wq[(size_t)(k0 + kk) * HC + (cc - 64)];
        }
        __syncthreads();
        #pragma unroll 4
        for (int kk = 0; kk < 32; kk++) {
            float a[4];
            #pragma unroll
            for (int ri = 0; ri < 4; ri++) a[ri] = Xs[tr * 4 + ri][kk];
            float b[8];
            float4 b0 = *(const float4*)&Ws[kk][tc * 8];
            float4 b1 = *(const float4*)&Ws[kk][tc * 8 + 4];
            b[0]=b0.x; b[1]=b0.y; b[2]=b0.z; b[3]=b0.w;
            b[4]=b1.x; b[5]=b1.y; b[6]=b1.z; b[7]=b1.w;
            #pragma unroll
            for (int ri = 0; ri < 4; ri++)
                #pragma unroll
                for (int ci = 0; ci < 8; ci++) acc[ri][ci] += a[ri] * b[ci];
        }
        __syncthreads();
    }

    // epilogue: bias; Q -> clamp + store; P -> LDS for LN
    #pragma unroll
    for (int ri = 0; ri < 4; ri++) {
        int rloc = tr * 4 + ri;
        size_t r = (size_t)(row0 + rloc);
        #pragma unroll
        for (int ci = 0; ci < 8; ci++) {
            int col = tc * 8 + ci;
            float v = acc[ri][ci];
            if (col < 64) {
                Ps[rloc][col] = v + bp[col];
            } else {
                int qc = col - 64;
                v += bq[qc];
                v = fminf(fmaxf(v, -20.f), 20.f);
                Qpre[r * HC + qc] = v;
            }
        }
    }
    __syncthreads();

    // LayerNorm over 64 channels, one wave per row
    const int wave = t >> 6, lane = t & 63;
    for (int rr = wave * 16; rr < wave * 16 + 16; rr++) {
        float v = Ps[rr][lane];
        float s = v;
        #pragma unroll
        for (int m = 32; m >= 1; m >>= 1) s += __shfl_xor(s, m, 64);
        float mean = s * (1.f / 64.f);
        float d = v - mean;
        float s2 = d * d;
        #pragma unroll
        for (int m = 32; m >= 1; m >>= 1) s2 += __shfl_xor(s2, m, 64);
        float var = s2 * (1.f / 64.f);
        float o = d * rsqrtf(var + 1e-5f) * gp[lane] + betap[lane];
        P[(size_t)(row0 + rr) * HC + lane] = o;
    }
}

// ---------------- Kernel 2: Q max over K axis + exp, IN PLACE on Qpre ----------
// Element (k,l,ch) is read and written only by thread (ch, k>>5); the barrier
// separates the max-pass reads from the exp writes.
__global__ __launch_bounds__(256) void k_qfin(float* __restrict__ Qpre)
{
    const int l = blockIdx.x;
    const int t = threadIdx.x;
    const int ch = t & 63, kq = t >> 6;
    __shared__ float red[4][64];
    float m = -1e30f;
    for (int kk = 0; kk < 32; kk++) {
        int k = kq * 32 + kk;
        m = fmaxf(m, Qpre[(size_t)k * LHC + l * HC + ch]);
    }
    red[kq][ch] = m;
    __syncthreads();
    m = fmaxf(fmaxf(red[0][ch], red[1][ch]), fmaxf(red[2][ch], red[3][ch]));
    for (int kk = 0; kk < 32; kk++) {
        int k = kq * 32 + kk;
        size_t idx = (size_t)k * LHC + l * HC + ch;
        Qpre[idx] = __expf(Qpre[idx] - m);
    }
}

// ---------------- Kernel 3: fused X/Y Gram blocks, ratio, out-GEMM, LN, relu ----
// Block: i = bid>>4 (row), j0 = (bid&15)*16 (16 j's). 256 threads.
// Phase A lane map: h = t>>6 (head=wave); within wave: p = bits0-3 (which j),
// qc = bit4, qr = bit5 -> thread owns the 8x8 sub-tile [qr*8,+8) x [qc*8,+8)
// of the 16x16 per-(i,j,h) X and Y blocks. PQ is formed on the fly (P*Q).
__global__ __launch_bounds__(256, 2) void k_agg(
    const float* __restrict__ P, const float* __restrict__ Q,
    const float* __restrict__ x2d, const float* __restrict__ Wo,
    const float* __restrict__ bo, const float* __restrict__ go,
    const float* __restrict__ betao, float* __restrict__ out)
{
    __shared__ float smem[18624];   // 74.5 KB, reused across phases
    // Phase A layout:
    float* Ai = smem;                       // [KC][64]      PQ rows of i
    float* Bi = smem + 512;                 // [KC][64]      Q  rows of i
    float* Aj = smem + 1024;                // [TP][AJ_STR]  PQ rows of j
    float* Bj = smem + 1024 + TP * AJ_STR;  // [TP][AJ_STR]  Q  rows of j   (end 17536)

    const int t = threadIdx.x;
    const int i  = blockIdx.x >> 4;
    const int j0 = (blockIdx.x & 15) * TP;

    const int h  = t >> 6;
    const int l6 = t & 63;
    const int p  = l6 & 15;
    const int qr = (l6 >> 5) & 1;
    const int qc = (l6 >> 4) & 1;
    const int h16 = h * 16;

    float aX[8][8], aY[8][8];
    #pragma unroll
    for (int a = 0; a < 8; a++)
        #pragma unroll
        for (int b = 0; b < 8; b++) { aX[a][b] = 0.f; aY[a][b] = 0.f; }

    const float* AiB = Ai + h16 + qr * 8;
    const float* BiB = Bi + h16 + qr * 8;
    const float* AjB = Aj + p * AJ_STR + h16 + qc * 8;
    const float* BjB = Bj + p * AJ_STR + h16 + qc * 8;

    // ---- Phase A: accumulate 16x16 X/Y blocks over K=128 ----
    for (int kc = 0; kc < KNUM; kc += KC) {
        __syncthreads();
        // stage Ai/Bi: KC*16 float4 = 128 (first 128 threads)
        if (t < KC * 16) {
            int kk = t >> 4, c4 = (t & 15) * 4;
            size_t g = (size_t)(kc + kk) * LHC + (size_t)i * HC + c4;
            float4 pv = *(const float4*)&P[g];
            float4 qv = *(const float4*)&Q[g];
            *(float4*)&Bi[kk * 64 + c4] = qv;
            *(float4*)&Ai[kk * 64 + c4] = make_float4(pv.x*qv.x, pv.y*qv.y, pv.z*qv.z, pv.w*qv.w);
        }
        // stage Aj/Bj: TP*KC*16 = 2048 float4, 8 iters (contiguous 16-lane runs)
        #pragma unroll
        for (int it = 0; it < 8; it++) {
            int idx = t + it * 256;
            int pp = idx >> 7, kk = (idx >> 4) & 7, c4 = (idx & 15) * 4;
            size_t g = (size_t)(kc + kk) * LHC + (size_t)(j0 + pp) * HC + c4;
            float4 pv = *(const float4*)&P[g];
            float4 qv = *(const float4*)&Q[g];
            *(float4*)&Bj[pp * AJ_STR + kk * 64 + c4] = qv;
            *(float4*)&Aj[pp * AJ_STR + kk * 64 + c4] =
                make_float4(pv.x*qv.x, pv.y*qv.y, pv.z*qv.z, pv.w*qv.w);
        }
        __syncthreads();
        #pragma unroll
        for (int kk = 0; kk < KC; kk++) {
            float a8[8], b8[8], aj8[8], bj8[8];
            *(float4*)&a8[0]  = *(const float4*)(AiB + kk * 64);
            *(float4*)&a8[4]  = *(const float4*)(AiB + kk * 64 + 4);
            *(float4*)&b8[0]  = *(const float4*)(BiB + kk * 64);
            *(float4*)&b8[4]  = *(const float4*)(BiB + kk * 64 + 4);
            *(float4*)&aj8[0] = *(const float4*)(AjB + kk * 64);
            *(float4*)&aj8[4] = *(const float4*)(AjB + kk * 64 + 4);
            *(float4*)&bj8[0] = *(const float4*)(BjB + kk * 64);
            *(float4*)&bj8[4] = *(const float4*)(BjB + kk * 64 + 4);
            #pragma unroll
            for (int ci = 0; ci < 8; ci++)
                #pragma unroll
                for (int cj = 0; cj < 8; cj++) {
                    aX[ci][cj] += a8[ci] * aj8[cj];
                    aY[ci][cj] += b8[ci] * bj8[cj];
                }
        }
    }

    // ---- Phase B layout ----
    float* xl   = smem;                     // [TP][XL_STR]  16448
    float* x2dl = smem + TP * XL_STR;       // [TP][128]     2048  (end 18496)
    float* red1 = smem + TP * XL_STR + TP * D2;        // [TP*4]
    float* red2 = smem + TP * XL_STR + TP * D2 + 64;   // [TP*4]
    __syncthreads();

    // ratio -> xl   (agg2d channel index r = h*256 + ci_g*16 + cj_g)
    #pragma unroll
    for (int ci = 0; ci < 8; ci++) {
        int rrow = h * 256 + (qr * 8 + ci) * 16 + qc * 8;
        #pragma unroll
        for (int cjv = 0; cjv < 2; cjv++) {
            float4 v;
            v.x = aX[ci][cjv*4+0] / (aY[ci][cjv*4+0] + 1e-6f);
            v.y = aX[ci][cjv*4+1] / (aY[ci][cjv*4+1] + 1e-6f);
            v.z = aX[ci][cjv*4+2] / (aY[ci][cjv*4+2] + 1e-6f);
            v.w = aX[ci][cjv*4+3] / (aY[ci][cjv*4+3] + 1e-6f);
            *(float4*)&xl[p * XL_STR + rrow + cjv * 4] = v;
        }
    }
    #pragma unroll
    for (int it = 0; it < 8; it++) {
        int idx = t + it * 256;           // TP*128 = 2048
        int pp = idx >> 7, d = idx & 127;
        x2dl[pp * D2 + d] = x2d[((size_t)i * LL + (j0 + pp)) * D2 + d];
    }
    __syncthreads();

    // ---- Phase B: out GEMM (1152 x 256) over 16 j's ----
    const int n = t;
    float accO[TP];
    float bon = bo[n];
    #pragma unroll
    for (int pp = 0; pp < TP; pp++) accO[pp] = bon;

    for (int r = 0; r < 1024; r += 4) {
        float w0 = Wo[(size_t)(r + 0) * AGG + n];
        float w1 = Wo[(size_t)(r + 1) * AGG + n];
        float w2 = Wo[(size_t)(r + 2) * AGG + n];
        float w3 = Wo[(size_t)(r + 3) * AGG + n];
        #pragma unroll
        for (int pp = 0; pp < TP; pp++) {
            float4 xv = *(const float4*)&xl[pp * XL_STR + r];
            accO[pp] += xv.x * w0 + xv.y * w1 + xv.z * w2 + xv.w * w3;
        }
    }
    for (int d = 0; d < D2; d += 4) {
        float w0 = Wo[(size_t)(1024 + d + 0) * AGG + n];
        float w1 = Wo[(size_t)(1024 + d + 1) * AGG + n];
        float w2 = Wo[(size_t)(1024 + d + 2) * AGG + n];
        float w3 = Wo[(size_t)(1024 + d + 3) * AGG + n];
        #pragma unroll
        for (int pp = 0; pp < TP; pp++) {
            float4 xv = *(const float4*)&x2dl[pp * D2 + d];
            accO[pp] += xv.x * w0 + xv.y * w1 + xv.z * w2 + xv.w * w3;
        }
    }

    // ---- LayerNorm across 256 channels per (i, j0+pp), then relu + store ----
    const int lane = t & 63, wv = t >> 6;
    float gn = go[n], bn = betao[n];
    #pragma unroll
    for (int pp = 0; pp < TP; pp++) {
        float s = accO[pp];
        #pragma unroll
        for (int m = 32; m >= 1; m >>= 1) s += __shfl_xor(s, m, 64);
        if (lane == 0) red1[pp * 4 + wv] = s;
    }
    __syncthreads();
    #pragma unroll
    for (int pp = 0; pp < TP; pp++) {
        float mean = (red1[pp*4] + red1[pp*4+1] + red1[pp*4+2] + red1[pp*4+3]) * (1.f / 256.f);
        float d = accO[pp] - mean;
        accO[pp] = d;
        float s2 = d * d;
        #pragma unroll
        for (int m = 32; m >= 1; m >>= 1) s2 += __shfl_xor(s2, m, 64);
        if (lane == 0) red2[pp * 4 + wv] = s2;
    }
    __syncthreads();
    #pragma unroll
    for (int pp = 0; pp < TP; pp++) {
        float var = (red2[pp*4] + red2[pp*4+1] + red2[pp*4+2] + red2[pp*4+3]) * (1.f / 256.f);
        float o = accO[pp] * rsqrtf(var + 1e-5f) * gn + bn;
        o = fmaxf(o, 0.f);
        out[((size_t)i * LL + (j0 + pp)) * AGG + n] = o;
    }
}

// ---------------- launch ----------------
extern "C" void kernel_launch(void* const* d_in, const int* in_sizes, int n_in,
                              void* d_out, int out_size, void* d_ws, size_t ws_size,
                              hipStream_t stream)
{
    const float* x1d   = (const float*)d_in[0];
    const float* x2d   = (const float*)d_in[1];
    const float* Wp    = (const float*)d_in[2];
    const float* bp    = (const float*)d_in[3];
    const float* gp    = (const float*)d_in[4];
    const float* betap = (const float*)d_in[5];
    const float* Wq    = (const float*)d_in[6];
    const float* bq    = (const float*)d_in[7];
    const float* Wo    = (const float*)d_in[8];
    const float* bo    = (const float*)d_in[9];
    const float* go    = (const float*)d_in[10];
    const float* betao = (const float*)d_in[11];
    float* out = (float*)d_out;

    float* P    = (float*)d_ws;               // 32768*64 floats = 8 MB
    float* Qpre = P + (size_t)M1 * HC;        // 8 MB; becomes Q in place

    hipLaunchKernelGGL(k_proj, dim3(M1 / 64), dim3(256), 0, stream,
                       x1d, Wp, bp, gp, betap, Wq, bq, P, Qpre);
    hipLaunchKernelGGL(k_qfin, dim3(LL), dim3(256), 0, stream, Qpre);
    hipLaunchKernelGGL(k_agg, dim3(LL * (LL / TP)), dim3(256), 0, stream,
                       P, Qpre, x2d, Wo, bo, go, betao, out);
}

// Round 8
// 1080.797 us; speedup vs baseline: 2.1849x; 2.1849x over previous
//
#include <hip/hip_runtime.h>
#include <math.h>

#define KNUM 128
#define LL   256
#define NINP 384
#define HC   64
#define NH   4
#define D2   128
#define AGG  256
#define LHC  (LL*HC)        // 16384
#define M1   (KNUM*LL)      // 32768
#define PROJ 1152
#define RSTR 1192           // xl row stride (u16): byte stride 2384 -> 2-way-optimal banks
#define NELEM 2097152       // M1*HC

typedef unsigned short u16;
typedef short bf16x8 __attribute__((ext_vector_type(8)));
typedef float f32x4 __attribute__((ext_vector_type(4)));
typedef unsigned short ushort8 __attribute__((ext_vector_type(8)));

// round-to-nearest-even fp32 -> bf16 (hi), and residual bf16 (lo)
__device__ __forceinline__ void bsplit(float x, u16 &h, u16 &l) {
    unsigned u = __float_as_uint(x);
    unsigned hb = (u + 0x7FFFu + ((u >> 16) & 1u)) >> 16;
    h = (u16)hb;
    float r = x - __uint_as_float(hb << 16);
    unsigned u2 = __float_as_uint(r);
    l = (u16)((u2 + 0x7FFFu + ((u2 >> 16) & 1u)) >> 16);
}

// ---------------- Kernel 1: fused dual GEMM (P,Q) + bias + LN(P) + clamp(Q) ----
// (unchanged from the verified fp32 kernel)
__global__ __launch_bounds__(256) void k_proj(
    const float* __restrict__ x1d, const float* __restrict__ Wp, const float* __restrict__ bp,
    const float* __restrict__ gp, const float* __restrict__ betap,
    const float* __restrict__ Wq, const float* __restrict__ bq,
    float* __restrict__ P, float* __restrict__ Qpre)
{
    __shared__ float Xs[64][33];
    __shared__ float Ws[32][128];
    __shared__ float Ps[64][65];
    const int t = threadIdx.x;
    const int row0 = blockIdx.x * 64;
    const int tc = t & 15, tr = t >> 4;
    float acc[4][8];
    #pragma unroll
    for (int a = 0; a < 4; a++)
        #pragma unroll
        for (int b = 0; b < 8; b++) acc[a][b] = 0.f;

    for (int k0 = 0; k0 < NINP; k0 += 32) {
        for (int idx = t; idx < 64 * 32; idx += 256) {
            int r = idx >> 5, kk = idx & 31;
            Xs[r][kk] = x1d[(size_t)(row0 + r) * NINP + k0 + kk];
        }
        for (int idx = t; idx < 32 * 128; idx += 256) {
            int kk = idx >> 7, cc = idx & 127;
            Ws[kk][cc] = (cc < 64) ? Wp[(size_t)(k0 + kk) * HC + cc]
                                   : Wq[(size_t)(k0 + kk) * HC + (cc - 64)];
        }
        __syncthreads();
        #pragma unroll 4
        for (int kk = 0; kk < 32; kk++) {
            float a[4];
            #pragma unroll
            for (int ri = 0; ri < 4; ri++) a[ri] = Xs[tr * 4 + ri][kk];
            float b[8];
            float4 b0 = *(const float4*)&Ws[kk][tc * 8];
            float4 b1 = *(const float4*)&Ws[kk][tc * 8 + 4];
            b[0]=b0.x; b[1]=b0.y; b[2]=b0.z; b[3]=b0.w;
            b[4]=b1.x; b[5]=b1.y; b[6]=b1.z; b[7]=b1.w;
            #pragma unroll
            for (int ri = 0; ri < 4; ri++)
                #pragma unroll
                for (int ci = 0; ci < 8; ci++) acc[ri][ci] += a[ri] * b[ci];
        }
        __syncthreads();
    }

    #pragma unroll
    for (int ri = 0; ri < 4; ri++) {
        int rloc = tr * 4 + ri;
        size_t r = (size_t)(row0 + rloc);
        #pragma unroll
        for (int ci = 0; ci < 8; ci++) {
            int col = tc * 8 + ci;
            float v = acc[ri][ci];
            if (col < 64) {
                Ps[rloc][col] = v + bp[col];
            } else {
                int qc = col - 64;
                v += bq[qc];
                v = fminf(fmaxf(v, -20.f), 20.f);
                Qpre[r * HC + qc] = v;
            }
        }
    }
    __syncthreads();

    const int wave = t >> 6, lane = t & 63;
    for (int rr = wave * 16; rr < wave * 16 + 16; rr++) {
        float v = Ps[rr][lane];
        float s = v;
        #pragma unroll
        for (int m = 32; m >= 1; m >>= 1) s += __shfl_xor(s, m, 64);
        float mean = s * (1.f / 64.f);
        float d = v - mean;
        float s2 = d * d;
        #pragma unroll
        for (int m = 32; m >= 1; m >>= 1) s2 += __shfl_xor(s2, m, 64);
        float var = s2 * (1.f / 64.f);
        float o = d * rsqrtf(var + 1e-5f) * gp[lane] + betap[lane];
        P[(size_t)(row0 + rr) * HC + lane] = o;
    }
}

// ---------------- Kernel 2: Q max/exp + build transposed split-bf16 planes ------
// Output planes layout: [l][64ch][128k] u16 (bf16), one array per {PQ,Q}x{hi,lo}.
__global__ __launch_bounds__(256) void k_qfin(
    const float* __restrict__ P, const float* __restrict__ Qpre,
    u16* __restrict__ PQhi, u16* __restrict__ PQlo,
    u16* __restrict__ Qhi,  u16* __restrict__ Qlo)
{
    __shared__ float qs[128][66];
    __shared__ float ps[128][66];
    __shared__ float red[4][64];
    const int l = blockIdx.x, t = threadIdx.x;
    const int ch = t & 63, kq = t >> 6;

    float m = -1e30f;
    for (int kk = 0; kk < 32; kk++)
        m = fmaxf(m, Qpre[(size_t)(kq * 32 + kk) * LHC + l * HC + ch]);
    red[kq][ch] = m;
    __syncthreads();
    m = fmaxf(fmaxf(red[0][ch], red[1][ch]), fmaxf(red[2][ch], red[3][ch]));
    for (int kk = 0; kk < 32; kk++) {
        int k = kq * 32 + kk;
        size_t g = (size_t)k * LHC + l * HC + ch;
        float q = __expf(Qpre[g] - m);
        qs[k][ch] = q;
        ps[k][ch] = q * P[g];
    }
    __syncthreads();

    // transpose + split + write: thread (ch2 = t>>2, ks = t&3) owns 32 consecutive k
    const int ch2 = t >> 2, ks = t & 3;
    size_t base = (size_t)l * 8192 + (size_t)ch2 * 128 + ks * 32;
    for (int k8 = 0; k8 < 4; k8++) {
        ushort8 qh, ql, ph, pl;
        #pragma unroll
        for (int e = 0; e < 8; e++) {
            int k = ks * 32 + k8 * 8 + e;
            u16 hh, ll;
            bsplit(qs[k][ch2], hh, ll); qh[e] = hh; ql[e] = ll;
            bsplit(ps[k][ch2], hh, ll); ph[e] = hh; pl[e] = ll;
        }
        *(ushort8*)&Qhi [base + k8 * 8] = qh;
        *(ushort8*)&Qlo [base + k8 * 8] = ql;
        *(ushort8*)&PQhi[base + k8 * 8] = ph;
        *(ushort8*)&PQlo[base + k8 * 8] = pl;
    }
}

// ---------------- Kernel 2b: Wo -> WoT split planes [n][1152r] ------------------
__global__ __launch_bounds__(256) void k_prep(
    const float* __restrict__ Wo, u16* __restrict__ WoThi, u16* __restrict__ WoTlo)
{
    __shared__ float ws[16][260];
    const int t = threadIdx.x, r0 = blockIdx.x * 16;
    for (int rr = 0; rr < 16; rr++)
        ws[rr][t] = Wo[(size_t)(r0 + rr) * AGG + t];
    __syncthreads();
    ushort8 h0, l0, h1, l1;
    #pragma unroll
    for (int e = 0; e < 8; e++) {
        u16 hh, ll;
        bsplit(ws[e][t], hh, ll);     h0[e] = hh; l0[e] = ll;
        bsplit(ws[8 + e][t], hh, ll); h1[e] = hh; l1[e] = ll;
    }
    size_t base = (size_t)t * PROJ + r0;
    *(ushort8*)&WoThi[base]     = h0;
    *(ushort8*)&WoThi[base + 8] = h1;
    *(ushort8*)&WoTlo[base]     = l0;
    *(ushort8*)&WoTlo[base + 8] = l1;
}

// ---------------- Kernel 3: MFMA Gram (X,Y) -> ratio -> MFMA out-GEMM -> LN -----
// Block: (2 i-rows, 16 j) ; 512 threads = 8 waves.
// Wave w: Gram: i2 = w>>2, j-quad = w&3 (4 j's), all 4 heads, X and Y.
// Phase B: wave w handles n-tiles {2w, 2w+1} for BOTH 16-row M-tiles.
__global__ __launch_bounds__(512, 2) void k_agg(
    const u16* __restrict__ PQhi, const u16* __restrict__ PQlo,
    const u16* __restrict__ Qhi,  const u16* __restrict__ Qlo,
    const u16* __restrict__ WoThi, const u16* __restrict__ WoTlo,
    const float* __restrict__ x2d, const float* __restrict__ bo,
    const float* __restrict__ go,  const float* __restrict__ betao,
    float* __restrict__ out)
{
    __shared__ __align__(16) u16 smem[76800];      // 153.6 KB
    u16* xlhi = smem;                               // [32][RSTR]
    u16* xllo = smem + 32 * RSTR;                   // +38144
    u16* Ajh  = smem;                               // phase-A aliases: [16][16][40]
    u16* Ajl  = smem + 10240;
    u16* Aih  = smem + 20480;                       // [2][16][40]
    u16* Ail  = smem + 21760;
    float* redmem = (float*)(smem + 76288);         // 256 floats

    const int t = threadIdx.x;
    const int ipair = blockIdx.x >> 4, jg = blockIdx.x & 15;
    const int i0 = ipair * 2, j0 = jg * 16;
    const int w  = t >> 6,  l6 = t & 63;
    const int lc = l6 & 15, lg = l6 >> 4;           // lane col / k-group
    const int wi2 = w >> 2, wjq = w & 3;

    f32x4 acc[2][4][4];                             // [X/Y][head][jj]
    const f32x4 z4 = {0.f, 0.f, 0.f, 0.f};
    #pragma unroll
    for (int p = 0; p < 2; p++)
        #pragma unroll
        for (int h = 0; h < 4; h++)
            #pragma unroll
            for (int jj = 0; jj < 4; jj++) acc[p][h][jj] = z4;

    // ---- Phase A: Gram via 16x16x32 bf16 MFMA, split 3-product ----
    #pragma unroll
    for (int p = 0; p < 2; p++) {
        const u16* Sh = p ? Qhi : PQhi;
        const u16* Sl = p ? Qlo : PQlo;
        #pragma unroll
        for (int h = 0; h < 4; h++) {
            for (int kw = 0; kw < 4; kw++) {
                __syncthreads();
                for (int idx = t; idx < 2304; idx += 512) {
                    if (idx < 2048) {
                        int pl = idx >> 10, rem = idx & 1023;
                        int j = rem >> 6, ch = (rem >> 2) & 15, q = rem & 3;
                        ushort8 v = *(const ushort8*)&(pl ? Sl : Sh)
                            [(size_t)(j0 + j) * 8192 + (h * 16 + ch) * 128 + kw * 32 + q * 8];
                        *(ushort8*)&(pl ? Ajl : Ajh)[j * 640 + ch * 40 + q * 8] = v;
                    } else {
                        int idx2 = idx - 2048;
                        int pl = idx2 >> 7, rem = idx2 & 127;
                        int i2 = rem >> 6, ch = (rem >> 2) & 15, q = rem & 3;
                        ushort8 v = *(const ushort8*)&(pl ? Sl : Sh)
                            [(size_t)(i0 + i2) * 8192 + (h * 16 + ch) * 128 + kw * 32 + q * 8];
                        *(ushort8*)&(pl ? Ail : Aih)[i2 * 640 + ch * 40 + q * 8] = v;
                    }
                }
                __syncthreads();
                bf16x8 ah = *(const bf16x8*)&Aih[wi2 * 640 + lc * 40 + lg * 8];
                bf16x8 al = *(const bf16x8*)&Ail[wi2 * 640 + lc * 40 + lg * 8];
                #pragma unroll
                for (int jj = 0; jj < 4; jj++) {
                    int j = wjq * 4 + jj;
                    bf16x8 bh = *(const bf16x8*)&Ajh[j * 640 + lc * 40 + lg * 8];
                    bf16x8 bl = *(const bf16x8*)&Ajl[j * 640 + lc * 40 + lg * 8];
                    f32x4 a = acc[p][h][jj];
                    a = __builtin_amdgcn_mfma_f32_16x16x32_bf16(al, bh, a, 0, 0, 0);
                    a = __builtin_amdgcn_mfma_f32_16x16x32_bf16(ah, bl, a, 0, 0, 0);
                    a = __builtin_amdgcn_mfma_f32_16x16x32_bf16(ah, bh, a, 0, 0, 0);
                    acc[p][h][jj] = a;
                }
            }
        }
    }

    // ---- ratio -> xl (split bf16), + x2d tail channels ----
    __syncthreads();     // all Gram LDS reads done; staging area is dead
    #pragma unroll
    for (int h = 0; h < 4; h++)
        #pragma unroll
        for (int jj = 0; jj < 4; jj++) {
            int row = wi2 * 16 + wjq * 4 + jj;
            #pragma unroll
            for (int rg = 0; rg < 4; rg++) {
                float xv = acc[0][h][jj][rg] / (acc[1][h][jj][rg] + 1e-6f);
                int r = h * 256 + (lg * 4 + rg) * 16 + lc;   // agg2d channel
                u16 hh, ll;
                bsplit(xv, hh, ll);
                xlhi[row * RSTR + r] = hh;
                xllo[row * RSTR + r] = ll;
            }
        }
    for (int idx = t; idx < 4096; idx += 512) {
        int row = idx >> 7, d = idx & 127;
        float v = x2d[(size_t)((i0 + (row >> 4)) * LL + (j0 + (row & 15))) * D2 + d];
        u16 hh, ll;
        bsplit(v, hh, ll);
        xlhi[row * RSTR + 1024 + d] = hh;
        xllo[row * RSTR + 1024 + d] = ll;
    }
    __syncthreads();

    // ---- Phase B: out = xl(1152) @ Wo -> 32 rows x 256 n, MFMA split ----
    f32x4 accO[2][2];
    accO[0][0] = z4; accO[0][1] = z4; accO[1][0] = z4; accO[1][1] = z4;
    const int nt0 = w * 2;
    for (int ks = 0; ks < 36; ks++) {
        bf16x8 a0h = *(const bf16x8*)&xlhi[(size_t)lc * RSTR + ks * 32 + lg * 8];
        bf16x8 a0l = *(const bf16x8*)&xllo[(size_t)lc * RSTR + ks * 32 + lg * 8];
        bf16x8 a1h = *(const bf16x8*)&xlhi[(size_t)(16 + lc) * RSTR + ks * 32 + lg * 8];
        bf16x8 a1l = *(const bf16x8*)&xllo[(size_t)(16 + lc) * RSTR + ks * 32 + lg * 8];
        #pragma unroll
        for (int n2 = 0; n2 < 2; n2++) {
            size_t wb = (size_t)((nt0 + n2) * 16 + lc) * PROJ + ks * 32 + lg * 8;
            bf16x8 bh = *(const bf16x8*)&WoThi[wb];
            bf16x8 bl = *(const bf16x8*)&WoTlo[wb];
            f32x4 a = accO[0][n2];
            a = __builtin_amdgcn_mfma_f32_16x16x32_bf16(a0l, bh, a, 0, 0, 0);
            a = __builtin_amdgcn_mfma_f32_16x16x32_bf16(a0h, bl, a, 0, 0, 0);
            a = __builtin_amdgcn_mfma_f32_16x16x32_bf16(a0h, bh, a, 0, 0, 0);
            accO[0][n2] = a;
            f32x4 b = accO[1][n2];
            b = __builtin_amdgcn_mfma_f32_16x16x32_bf16(a1l, bh, b, 0, 0, 0);
            b = __builtin_amdgcn_mfma_f32_16x16x32_bf16(a1h, bl, b, 0, 0, 0);
            b = __builtin_amdgcn_mfma_f32_16x16x32_bf16(a1h, bh, b, 0, 0, 0);
            accO[1][n2] = b;
        }
    }

    // ---- scatter accO -> out_lds[32][260] (aliases xl; xl dead) ----
    __syncthreads();
    float* out_lds = (float*)smem;
    #pragma unroll
    for (int mt = 0; mt < 2; mt++)
        #pragma unroll
        for (int n2 = 0; n2 < 2; n2++)
            #pragma unroll
            for (int rg = 0; rg < 4; rg++)
                out_lds[(mt * 16 + lg * 4 + rg) * 260 + (nt0 + n2) * 16 + lc] = accO[mt][n2][rg];
    __syncthreads();

    // ---- LayerNorm over 256 channels per row, relu, store ----
    const int n = t & 255, half = t >> 8;
    const int lane = t & 63, wv4 = (t >> 6) & 3;
    float bon = bo[n], gn = go[n], bn = betao[n];
    float* red1 = redmem;          // [32][4]
    float* red2 = redmem + 128;    // [32][4]
    float accR[16];
    #pragma unroll
    for (int pp = 0; pp < 16; pp++) {
        int row = half * 16 + pp;
        float v = out_lds[row * 260 + n] + bon;
        accR[pp] = v;
        float s = v;
        #pragma unroll
        for (int m = 32; m >= 1; m >>= 1) s += __shfl_xor(s, m, 64);
        if (lane == 0) red1[row * 4 + wv4] = s;
    }
    __syncthreads();
    #pragma unroll
    for (int pp = 0; pp < 16; pp++) {
        int row = half * 16 + pp;
        float mean = (red1[row*4] + red1[row*4+1] + red1[row*4+2] + red1[row*4+3]) * (1.f / 256.f);
        float d = accR[pp] - mean;
        accR[pp] = d;
        float s2 = d * d;
        #pragma unroll
        for (int m = 32; m >= 1; m >>= 1) s2 += __shfl_xor(s2, m, 64);
        if (lane == 0) red2[row * 4 + wv4] = s2;
    }
    __syncthreads();
    #pragma unroll
    for (int pp = 0; pp < 16; pp++) {
        int row = half * 16 + pp;
        float var = (red2[row*4] + red2[row*4+1] + red2[row*4+2] + red2[row*4+3]) * (1.f / 256.f);
        float o = accR[pp] * rsqrtf(var + 1e-5f) * gn + bn;
        o = fmaxf(o, 0.f);
        out[((size_t)(i0 + half) * LL + (j0 + pp)) * AGG + n] = o;
    }
}

// ---------------- launch ----------------
extern "C" void kernel_launch(void* const* d_in, const int* in_sizes, int n_in,
                              void* d_out, int out_size, void* d_ws, size_t ws_size,
                              hipStream_t stream)
{
    const float* x1d   = (const float*)d_in[0];
    const float* x2d   = (const float*)d_in[1];
    const float* Wp    = (const float*)d_in[2];
    const float* bp    = (const float*)d_in[3];
    const float* gp    = (const float*)d_in[4];
    const float* betap = (const float*)d_in[5];
    const float* Wq    = (const float*)d_in[6];
    const float* bq    = (const float*)d_in[7];
    const float* Wo    = (const float*)d_in[8];
    const float* bo    = (const float*)d_in[9];
    const float* go    = (const float*)d_in[10];
    const float* betao = (const float*)d_in[11];
    float* out = (float*)d_out;

    float* P    = (float*)d_ws;                 // 8 MB
    float* Qpre = P + NELEM;                    // 8 MB
    u16* PQhi = (u16*)(Qpre + NELEM);           // 4 MB each
    u16* PQlo = PQhi + NELEM;
    u16* Qhi  = PQlo + NELEM;
    u16* Qlo  = Qhi  + NELEM;
    u16* WoThi = Qlo + NELEM;                   // 0.59 MB each
    u16* WoTlo = WoThi + 294912;

    hipLaunchKernelGGL(k_prep, dim3(PROJ / 16), dim3(256), 0, stream, Wo, WoThi, WoTlo);
    hipLaunchKernelGGL(k_proj, dim3(M1 / 64), dim3(256), 0, stream,
                       x1d, Wp, bp, gp, betap, Wq, bq, P, Qpre);
    hipLaunchKernelGGL(k_qfin, dim3(LL), dim3(256), 0, stream,
                       P, Qpre, PQhi, PQlo, Qhi, Qlo);
    hipLaunchKernelGGL(k_agg, dim3((LL / 2) * (LL / 16)), dim3(512), 0, stream,
                       PQhi, PQlo, Qhi, Qlo, WoThi, WoTlo, x2d, bo, go, betao, out);
}